// Round 9
// baseline (13691.431 us; speedup 1.0000x reference)
//
#include <hip/hip_runtime.h>
#include <hip/hip_bf16.h>
#include <cmath>

// Problem constants
#define BB 256
#define TT 30
#define SS 62          // padded sequence length L+2
#define DM 768
#define NH 12
#define DFF 3072
#define NTOK (BB*SS)   // 15872 = 124*128

typedef unsigned short us16;
typedef __bf16 bf16x8 __attribute__((ext_vector_type(8)));
typedef float f32x4 __attribute__((ext_vector_type(4)));

__device__ __forceinline__ us16 f2b(float f){ __hip_bfloat16 t=__float2bfloat16(f); return *reinterpret_cast<us16*>(&t); }
__device__ __forceinline__ float b2f(us16 u){ __hip_bfloat16 t; *reinterpret_cast<us16*>(&t)=u; return __bfloat162float(t); }
__device__ __forceinline__ float dgelu(float x){ return 0.5f*x*(1.0f+erff(x*0.7071067811865475f)); }
__device__ __forceinline__ f32x4 mfma16(bf16x8 a, bf16x8 b, f32x4 c){ return __builtin_amdgcn_mfma_f32_16x16x32_bf16(a,b,c,0,0,0); }

// async global->LDS, 16B per lane. LDS dest is wave-uniform base + lane*16.
__device__ __forceinline__ void gload16(const void* g, void* l) {
    __builtin_amdgcn_global_load_lds(
        (__attribute__((address_space(1))) void*)(uintptr_t)g,
        (__attribute__((address_space(3))) void*)(uint32_t)(uintptr_t)l,
        16, 0, 0);
}

// ---------------------------------------------------------------------------
// Mask dtype detection: flag 1 = bool (byte), 0 = int32, 2 = int64.
// ---------------------------------------------------------------------------
__global__ __launch_bounds__(256) void detect_mask_kernel(
    const unsigned char* __restrict__ m, int* __restrict__ flag)
{
    __shared__ int sub4, oddw;
    if (threadIdx.x == 0) { sub4 = 0; oddw = 0; }
    __syncthreads();
    for (int j = threadIdx.x; j < BB*TT; j += blockDim.x) {
        unsigned char v = m[j];
        if (v) {
            if (j & 3) sub4 = 1;
            if ((j >> 2) & 1) oddw = 1;
        }
    }
    __syncthreads();
    if (threadIdx.x == 0) *flag = sub4 ? 1 : (oddw ? 0 : 2);
}

// ---------------------------------------------------------------------------
// fp32 -> bf16 conversion, 8 elems/thread. n8 = count/8.
// ---------------------------------------------------------------------------
__global__ __launch_bounds__(256) void cvt_kernel(
    const float* __restrict__ in, us16* __restrict__ out, int n8)
{
    int t = blockIdx.x*256 + threadIdx.x;
    if (t >= n8) return;
    const float4* s = (const float4*)(in + (long)t*8);
    float4 a = s[0], b = s[1];
    us16 tmp[8] = {f2b(a.x),f2b(a.y),f2b(a.z),f2b(a.w),f2b(b.x),f2b(b.y),f2b(b.z),f2b(b.w)};
    *(uint4*)(out + (long)t*8) = *(uint4*)tmp;
}

// Fused per-layer weight conversion.
__global__ __launch_bounds__(256) void cvt_layer_kernel(
    const float* __restrict__ qkv, const float* __restrict__ wo,
    const float* __restrict__ w1,  const float* __restrict__ w2,
    us16* __restrict__ dqkv, us16* __restrict__ dwo,
    us16* __restrict__ dw1,  us16* __restrict__ dw2)
{
    long t = (long)blockIdx.x*256 + threadIdx.x;
    const float* src; us16* dst; long off;
    if (t < 221184)      { src = qkv; dst = dqkv; off = t; }
    else if (t < 294912) { src = wo;  dst = dwo;  off = t - 221184; }
    else if (t < 589824) { src = w1;  dst = dw1;  off = t - 294912; }
    else                 { src = w2;  dst = dw2;  off = t - 589824; }
    const float4* s = (const float4*)(src + off*8);
    float4 a = s[0], b = s[1];
    us16 tmp[8] = {f2b(a.x),f2b(a.y),f2b(a.z),f2b(a.w),f2b(b.x),f2b(b.y),f2b(b.z),f2b(b.w)};
    *(uint4*)(dst + off*8) = *(uint4*)tmp;
}

// ---------------------------------------------------------------------------
// bf16 GEMM, m97-configuration: SINGLE 32KB LDS buffer, BK=64, 4 waves (2x2),
// __syncthreads drains, 5 blocks/CU (20 waves/CU) so cross-block wave overlap
// hides the vmcnt(0) drain (m114 mechanism).
//   out[m,n] = EPI( sum_k A[m,k]*W[n,k] + bias[n] )
// - global_load_lds dwordx4 staging (linear LDS dest).
// - Conflict-free XOR swizzle (round-5/6 proven, 0 conflicts): source col
//   block (lane&7)^(lane>>3) pre-swizzled on GLOBAL addr; read block
//   (kk*4+g)^(row&7).
// - Bijective XCD-aware grid remap (m204).
// - setprio(1) around MFMA: blocks at independent phases -> scheduler can
//   prefer MFMA waves (attn-regime, not lockstep-null regime).
// EPI: 0 = store bf16, 1 = gelu->bf16, 2 = fp32 residual add (out += v)
// ---------------------------------------------------------------------------
template<int EPI>
__global__ __launch_bounds__(256, 5) void gemm_bf(const us16* __restrict__ A,
    const us16* __restrict__ W, const float* __restrict__ bias,
    void* __restrict__ outv, int N, int K, int ntn)
{
    __shared__ us16 As[128*64];   // 16 KB
    __shared__ us16 Ws[128*64];   // 16 KB
    const int tid  = threadIdx.x;
    const int lane = tid & 63;
    const int wave = tid >> 6;
    const int wr = wave >> 1, wc = wave & 1;
    const int li = lane & 15, g = lane >> 4;

    // bijective XCD-aware remap (m204)
    const int nwg = gridDim.x;
    const int q8 = nwg >> 3, r8 = nwg & 7;
    const int xcd = blockIdx.x & 7, b8 = blockIdx.x >> 3;
    const int newlin = (xcd < r8 ? xcd*(q8+1) : r8*(q8+1) + (xcd - r8)*q8) + b8;
    const long tm = newlin / ntn, tn = newlin % ntn;

    // staging: chunk=wave*4+c covers rows chunk*8..+7; lane -> row chunk*8+(lane>>3),
    // source col block pre-swizzled: (lane&7)^(lane>>3)  [= (lane&7)^(row&7)]
    const int swzc = ((lane & 7) ^ (lane >> 3)) * 8;
    const us16* agp = A + (tm*128 + wave*32 + (lane>>3))*(long)K + swzc;
    const us16* wgp = W + (tn*128 + wave*32 + (lane>>3))*(long)K + swzc;

    // hoisted swizzled LDS read offsets (K-step-invariant)
    int aoff[2][4], woff[2][4];
    #pragma unroll
    for (int kk=0;kk<2;kk++) {
        #pragma unroll
        for (int mi=0;mi<4;mi++) {
            int r = wr*64 + mi*16 + li;
            aoff[kk][mi] = r*64 + ((kk*4 + g) ^ (r & 7))*8;
        }
        #pragma unroll
        for (int ni=0;ni<4;ni++) {
            int r = wc*64 + ni*16 + li;
            woff[kk][ni] = r*64 + ((kk*4 + g) ^ (r & 7))*8;
        }
    }

    f32x4 acc[4][4];
    #pragma unroll
    for (int i=0;i<4;i++)
        #pragma unroll
        for (int j=0;j<4;j++)
            #pragma unroll
            for (int r=0;r<4;r++) acc[i][j][r] = 0.f;

    for (int k0 = 0; k0 < K; k0 += 64) {
        #pragma unroll
        for (int c=0;c<4;c++) {
            gload16(agp + k0 + (long)c*8*K, &As[(wave*4+c)*512]);
            gload16(wgp + k0 + (long)c*8*K, &Ws[(wave*4+c)*512]);
        }
        __syncthreads();   // drains vmcnt(0): staged tile visible
        #pragma unroll
        for (int kk=0; kk<2; kk++) {
            bf16x8 afr[4], bfr[4];
            #pragma unroll
            for (int mi=0;mi<4;mi++) afr[mi] = *(const bf16x8*)(As + aoff[kk][mi]);
            #pragma unroll
            for (int ni=0;ni<4;ni++) bfr[ni] = *(const bf16x8*)(Ws + woff[kk][ni]);
            if (kk == 0) __builtin_amdgcn_s_setprio(1);
            #pragma unroll
            for (int mi=0;mi<4;mi++)
                #pragma unroll
                for (int ni=0;ni<4;ni++)
                    acc[mi][ni] = mfma16(afr[mi], bfr[ni], acc[mi][ni]);
        }
        __builtin_amdgcn_s_setprio(0);
        __syncthreads();   // reads retired before next stage overwrites
    }

    // epilogue: C layout col=lane&15, row=(lane>>4)*4+r
    const long rbase = tm*128 + wr*64 + (g*4);
    const long cbase = tn*128 + wc*64 + li;
    #pragma unroll
    for (int mi=0;mi<4;mi++) {
        #pragma unroll
        for (int ni=0;ni<4;ni++) {
            long col = cbase + ni*16;
            float bv = bias[col];
            #pragma unroll
            for (int r=0;r<4;r++) {
                long row = rbase + mi*16 + r;
                float v = acc[mi][ni][r] + bv;
                if constexpr (EPI == 0) {
                    ((us16*)outv)[row*(long)N + col] = f2b(v);
                } else if constexpr (EPI == 1) {
                    ((us16*)outv)[row*(long)N + col] = f2b(dgelu(v));
                } else {
                    float* o = (float*)outv;
                    o[row*(long)N + col] += v;
                }
            }
        }
    }
}

// ---------------------------------------------------------------------------
// Pack kernel: build fp32 residual stream h[b][62][768].
// ---------------------------------------------------------------------------
__global__ __launch_bounds__(256) void pack_kernel(
    const us16* __restrict__ e, const void* __restrict__ maskv,
    const int* __restrict__ flagp,
    const float* __restrict__ mod_emb, const float* __restrict__ day_emb,
    const float* __restrict__ readmit, const float* __restrict__ contrast,
    float* __restrict__ h, int* __restrict__ vlen_out)
{
    __shared__ int day_of[TT];
    __shared__ int nvalid;
    const int b = blockIdx.x, tid = threadIdx.x;
    if (tid == 0) {
        const int fl = *flagp;
        int c = 0;
        for (int t = 0; t < TT; t++) {
            int mv;
            if (fl == 1)      mv = ((const unsigned char*)maskv)[b*TT + t];
            else if (fl == 2) mv = ((const int*)maskv)[(b*TT + t)*2];
            else              mv = ((const int*)maskv)[b*TT + t];
            if (mv != 0) day_of[c++] = t;
        }
        nvalid = c;
        vlen_out[b] = 2*c;
    }
    __syncthreads();
    const int vl = 2*nvalid;
    for (int p = 0; p < SS; p++) {
        for (int d = tid; d < DM; d += 256) {
            float val;
            if (p < vl) {
                int day = day_of[p >> 1];
                int m = p & 1;
                int l = day*2 + m;
                val = b2f(e[((long)b*(TT*2) + l)*DM + d]) + mod_emb[m*DM + d] + day_emb[day*DM + d];
            } else if (p == vl || p == vl + 1) {
                float freq = expf(-(float)(d & ~1) * (9.2103403719761836f/768.f));
                float pe = (d & 1) ? cosf((float)p * freq) : sinf((float)p * freq);
                val = ((p == vl) ? readmit[d] : contrast[d]) + pe;
            } else {
                val = 0.f;
            }
            h[((long)b*SS + p)*DM + d] = val;
        }
    }
}

// ---------------------------------------------------------------------------
// LayerNorm: one wave per token row (768), fp32 in -> bf16 out (affine)
// ---------------------------------------------------------------------------
__global__ __launch_bounds__(256) void ln_kernel(
    const float* __restrict__ x, const float* __restrict__ w,
    const float* __restrict__ bprm, us16* __restrict__ z)
{
    const int row  = blockIdx.x*4 + (threadIdx.x >> 6);
    const int lane = threadIdx.x & 63;
    const float* xr = x + (long)row*DM;
    float4 v[3];
    float s = 0.f, s2 = 0.f;
    #pragma unroll
    for (int j=0;j<3;j++) {
        v[j] = *(const float4*)(xr + lane*4 + j*256);
        s  += v[j].x + v[j].y + v[j].z + v[j].w;
        s2 += v[j].x*v[j].x + v[j].y*v[j].y + v[j].z*v[j].z + v[j].w*v[j].w;
    }
    #pragma unroll
    for (int d=1; d<64; d<<=1) { s += __shfl_xor(s, d); s2 += __shfl_xor(s2, d); }
    const float m  = s * (1.f/768.f);
    const float var = s2 * (1.f/768.f) - m*m;
    const float rs = rsqrtf(var + 1e-5f);
    us16* zr = z + (long)row*DM;
    #pragma unroll
    for (int j=0;j<3;j++) {
        int c0 = lane*4 + j*256;
        float vv[4] = {v[j].x, v[j].y, v[j].z, v[j].w};
        ushort4 o;
        o.x = f2b((vv[0]-m)*rs*w[c0+0] + bprm[c0+0]);
        o.y = f2b((vv[1]-m)*rs*w[c0+1] + bprm[c0+1]);
        o.z = f2b((vv[2]-m)*rs*w[c0+2] + bprm[c0+2]);
        o.w = f2b((vv[3]-m)*rs*w[c0+3] + bprm[c0+3]);
        *(ushort4*)(zr + c0) = o;
    }
}

// ---------------------------------------------------------------------------
// Attention: one block (256 thr, 4 waves) per (batch, head). S=62 (pad 64).
// ---------------------------------------------------------------------------
__global__ __launch_bounds__(256) void attn_kernel(
    const us16* __restrict__ qkv, const int* __restrict__ vlenp,
    us16* __restrict__ ctx)
{
    __shared__ us16 Ql[64*64];
    __shared__ us16 Kl[64*64];
    __shared__ us16 Vt[64*64];
    __shared__ us16 Pl[4*16*64];
    const int b = blockIdx.x, hh = blockIdx.y;
    const int tid = threadIdx.x;
    const int vl = vlenp[b];

    {
        int s  = tid >> 2;
        int d0 = (tid & 3) * 16;
        if (s < SS) {
            long base = ((long)b*SS + s)*(3*DM) + hh*64 + d0;
            uint4 a0 = *(const uint4*)(qkv + base);
            uint4 a1 = *(const uint4*)(qkv + base + 8);
            *(uint4*)&Ql[s*64 + d0]     = a0;
            *(uint4*)&Ql[s*64 + d0 + 8] = a1;
            uint4 c0 = *(const uint4*)(qkv + base + DM);
            uint4 c1 = *(const uint4*)(qkv + base + DM + 8);
            *(uint4*)&Kl[s*64 + d0]     = c0;
            *(uint4*)&Kl[s*64 + d0 + 8] = c1;
            us16 vv[16];
            *(uint4*)&vv[0] = *(const uint4*)(qkv + base + 2*DM);
            *(uint4*)&vv[8] = *(const uint4*)(qkv + base + 2*DM + 8);
            #pragma unroll
            for (int j=0;j<16;j++) Vt[(d0+j)*64 + s] = vv[j];
        } else {
            uint4 zz = make_uint4(0,0,0,0);
            *(uint4*)&Ql[s*64 + d0] = zz; *(uint4*)&Ql[s*64 + d0 + 8] = zz;
            *(uint4*)&Kl[s*64 + d0] = zz; *(uint4*)&Kl[s*64 + d0 + 8] = zz;
            #pragma unroll
            for (int j=0;j<16;j++) Vt[(d0+j)*64 + s] = 0;
        }
    }
    __syncthreads();

    const int lane = tid & 63, wave = tid >> 6;
    const int li = lane & 15, g = lane >> 4;
    const int qbase = wave * 16;

    f32x4 sacc[4];
    #pragma unroll
    for (int kb=0; kb<4; kb++) {
        f32x4 a; a[0]=a[1]=a[2]=a[3]=0.f;
        #pragma unroll
        for (int dc=0; dc<2; dc++) {
            bf16x8 qa = *(const bf16x8*)&Ql[(qbase + li)*64 + dc*32 + g*8];
            bf16x8 ka = *(const bf16x8*)&Kl[(kb*16 + li)*64 + dc*32 + g*8];
            a = mfma16(qa, ka, a);
        }
        sacc[kb] = a;
    }

    float den[4];
    #pragma unroll
    for (int r=0;r<4;r++) {
        float sc[4]; float mx = -3e38f;
        #pragma unroll
        for (int kb=0;kb<4;kb++) {
            int key = kb*16 + li;
            float v = sacc[kb][r]*0.125f + ((key <= vl + 1) ? 0.f : -1e9f);
            sc[kb] = v; mx = fmaxf(mx, v);
        }
        #pragma unroll
        for (int d=1; d<16; d<<=1) mx = fmaxf(mx, __shfl_xor(mx, d));
        float sm = 0.f;
        #pragma unroll
        for (int kb=0;kb<4;kb++) {
            float e = expf(sc[kb] - mx);
            sm += e;
            Pl[wave*1024 + (g*4 + r)*64 + kb*16 + li] = f2b(e);
        }
        #pragma unroll
        for (int d=1; d<16; d<<=1) sm += __shfl_xor(sm, d);
        den[r] = sm;
    }
    __syncthreads();

    #pragma unroll
    for (int vb=0; vb<4; vb++) {
        f32x4 oa; oa[0]=oa[1]=oa[2]=oa[3]=0.f;
        #pragma unroll
        for (int kc=0; kc<2; kc++) {
            bf16x8 pa = *(const bf16x8*)&Pl[wave*1024 + li*64 + kc*32 + g*8];
            bf16x8 va = *(const bf16x8*)&Vt[(vb*16 + li)*64 + kc*32 + g*8];
            oa = mfma16(pa, va, oa);
        }
        #pragma unroll
        for (int r=0;r<4;r++) {
            int s = qbase + g*4 + r;
            if (s < SS)
                ctx[((long)b*SS + s)*DM + hh*64 + vb*16 + li] = f2b(oa[r] / den[r]);
        }
    }
}

// ---------------------------------------------------------------------------
// Head MLP
// ---------------------------------------------------------------------------
__global__ __launch_bounds__(384) void head_kernel(
    const float* __restrict__ h, const int* __restrict__ vlenp,
    const float* __restrict__ hW1, const float* __restrict__ hb1,
    const float* __restrict__ hlnw, const float* __restrict__ hlnb,
    const float* __restrict__ hW2, const float* __restrict__ hb2,
    float* __restrict__ out)
{
    __shared__ float tokS[DM];
    __shared__ float ps[6], ps2[6];
    const int b = blockIdx.x, tid = threadIdx.x;
    const float* tok = h + ((long)b*SS + vlenp[b])*DM;
    for (int i = tid; i < DM; i += 384) tokS[i] = tok[i];
    __syncthreads();

    const float* wrow = hW1 + (long)tid*DM;
    float acc = hb1[tid];
    for (int k = 0; k < DM; k += 4) {
        float4 wv = *(const float4*)(wrow + k);
        acc += tokS[k]*wv.x + tokS[k+1]*wv.y + tokS[k+2]*wv.z + tokS[k+3]*wv.w;
    }
    float s = acc, s2 = acc*acc;
    #pragma unroll
    for (int d=1; d<64; d<<=1) { s += __shfl_xor(s, d); s2 += __shfl_xor(s2, d); }
    const int wavei = tid >> 6, lane = tid & 63;
    if (lane == 0) { ps[wavei] = s; ps2[wavei] = s2; }
    __syncthreads();
    float S = 0.f, S2 = 0.f;
    for (int i=0;i<6;i++){ S += ps[i]; S2 += ps2[i]; }
    const float m = S * (1.f/384.f);
    const float var = S2 * (1.f/384.f) - m*m;
    const float rs = rsqrtf(var + 1e-5f);
    float z = (acc - m)*rs*hlnw[tid] + hlnb[tid];
    float part = dgelu(z) * hW2[tid];
    #pragma unroll
    for (int d=1; d<64; d<<=1) part += __shfl_xor(part, d);
    __syncthreads();
    if (lane == 0) ps[wavei] = part;
    __syncthreads();
    if (tid == 0) {
        float t = 0.f;
        for (int i=0;i<6;i++) t += ps[i];
        out[b] = t + hb2[0];
    }
}

// ---------------------------------------------------------------------------
extern "C" void kernel_launch(void* const* d_in, const int* in_sizes, int n_in,
                              void* d_out, int out_size, void* d_ws, size_t ws_size,
                              hipStream_t stream)
{
    (void)in_sizes; (void)n_in; (void)out_size; (void)ws_size;
    const float* x        = (const float*)d_in[0];
    const void*  mask     = d_in[1];
    const float* Wp       = (const float*)d_in[2];
    const float* bp       = (const float*)d_in[3];
    const float* mod_emb  = (const float*)d_in[4];
    const float* day_emb  = (const float*)d_in[5];
    const float* readmit  = (const float*)d_in[6];
    const float* contrast = (const float*)d_in[7];
    const float* WqkvS    = (const float*)d_in[8];
    const float* bqkvS    = (const float*)d_in[9];
    const float* WoS      = (const float*)d_in[10];
    const float* boS      = (const float*)d_in[11];
    const float* ln1w     = (const float*)d_in[12];
    const float* ln1b     = (const float*)d_in[13];
    const float* ln2w     = (const float*)d_in[14];
    const float* ln2b     = (const float*)d_in[15];
    const float* W1S      = (const float*)d_in[16];
    const float* b1S      = (const float*)d_in[17];
    const float* W2S      = (const float*)d_in[18];
    const float* b2S      = (const float*)d_in[19];
    const float* hW1      = (const float*)d_in[20];
    const float* hb1      = (const float*)d_in[21];
    const float* hlnw     = (const float*)d_in[22];
    const float* hlnb     = (const float*)d_in[23];
    const float* hW2      = (const float*)d_in[24];
    const float* hb2      = (const float*)d_in[25];
    float* out = (float*)d_out;

    // workspace layout (~193 MiB)
    char* ws = (char*)d_ws;
    float* h    = (float*)ws;                        // 48,758,784
    us16*  zb   = (us16*) (ws + 48758784);           // 24,379,392
    us16*  big  = (us16*) (ws + 73138176);           // 97,517,568 (qkv/ff/embed alias)
    us16*  wl   = (us16*) (ws + 170655744);          // 14,155,776 (per-layer bf16 weights)
    us16*  xb   = (us16*) (ws + 184811520);          // 7,864,320  (bf16 x)
    us16*  wpb  = (us16*) (ws + 192675840);          // 393,216    (bf16 Wp)
    int*   vlen = (int*)  (ws + 193069056);
    int*   mflag= (int*)  (ws + 193070080);
    us16*  qkvb = big;
    us16*  ffb  = big;
    us16*  eb   = big;
    us16* qkvw = wl;                         // 2304*768
    us16* wow  = wl + 1769472;               // 768*768
    us16* w1w  = wl + 2359296;               // 3072*768
    us16* w2w  = wl + 4718592;               // 768*3072

    detect_mask_kernel<<<1,256,0,stream>>>((const unsigned char*)mask, mflag);
    cvt_kernel<<<1920,256,0,stream>>>(x, xb, 491520);       // 15360*256/8
    cvt_kernel<<<96,256,0,stream>>>(Wp, wpb, 24576);        // 768*256/8
    // embed: e = gelu(x @ Wp^T + bp); grid 120*6=720
    gemm_bf<1><<<720,256,0,stream>>>(xb, wpb, bp, eb, DM, 256, 6);
    pack_kernel<<<256,256,0,stream>>>(eb, mask, mflag, mod_emb, day_emb, readmit, contrast, h, vlen);

    for (int l = 0; l < 12; l++) {
        cvt_layer_kernel<<<3456,256,0,stream>>>(
            WqkvS + (long)l*3*DM*DM, WoS + (long)l*DM*DM,
            W1S + (long)l*DFF*DM,    W2S + (long)l*DM*DFF,
            qkvw, wow, w1w, w2w);
        ln_kernel<<<NTOK/4,256,0,stream>>>(h, ln1w + l*DM, ln1b + l*DM, zb);
        gemm_bf<0><<<2232,256,0,stream>>>(zb, qkvw, bqkvS + l*3*DM, qkvb, 3*DM, DM, 18);   // 124*18
        attn_kernel<<<dim3(256,12),256,0,stream>>>(qkvb, vlen, zb);
        gemm_bf<2><<<744,256,0,stream>>>(zb, wow, boS + l*DM, h, DM, DM, 6);               // 124*6
        ln_kernel<<<NTOK/4,256,0,stream>>>(h, ln2w + l*DM, ln2b + l*DM, zb);
        gemm_bf<1><<<2976,256,0,stream>>>(zb, w1w, b1S + l*DFF, ffb, DFF, DM, 24);         // 124*24
        gemm_bf<2><<<744,256,0,stream>>>(ffb, w2w, b2S + l*DM, h, DM, DFF, 6);             // 124*6
    }

    head_kernel<<<256,384,0,stream>>>(h, vlen, hW1, hb1, hlnw, hlnb, hW2, hb2, out);
}

// Round 10
// 4152.833 us; speedup vs baseline: 3.2969x; 3.2969x over previous
//
#include <hip/hip_runtime.h>
#include <hip/hip_bf16.h>
#include <cmath>

// Problem constants
#define BB 256
#define TT 30
#define SS 62          // padded sequence length L+2
#define DM 768
#define NH 12
#define DFF 3072
#define NTOK (BB*SS)   // 15872 = 124*128

typedef unsigned short us16;
typedef __bf16 bf16x8 __attribute__((ext_vector_type(8)));
typedef float f32x4 __attribute__((ext_vector_type(4)));

__device__ __forceinline__ us16 f2b(float f){ __hip_bfloat16 t=__float2bfloat16(f); return *reinterpret_cast<us16*>(&t); }
__device__ __forceinline__ float b2f(us16 u){ __hip_bfloat16 t; *reinterpret_cast<us16*>(&t)=u; return __bfloat162float(t); }
__device__ __forceinline__ float dgelu(float x){ return 0.5f*x*(1.0f+erff(x*0.7071067811865475f)); }
__device__ __forceinline__ f32x4 mfma16(bf16x8 a, bf16x8 b, f32x4 c){ return __builtin_amdgcn_mfma_f32_16x16x32_bf16(a,b,c,0,0,0); }

// async global->LDS, 16B per lane. LDS dest is wave-uniform base + lane*16.
__device__ __forceinline__ void gload16(const void* g, void* l) {
    __builtin_amdgcn_global_load_lds(
        (__attribute__((address_space(1))) void*)(uintptr_t)g,
        (__attribute__((address_space(3))) void*)(uint32_t)(uintptr_t)l,
        16, 0, 0);
}

// ---------------------------------------------------------------------------
// Mask dtype detection: flag 1 = bool (byte), 0 = int32, 2 = int64.
// ---------------------------------------------------------------------------
__global__ __launch_bounds__(256) void detect_mask_kernel(
    const unsigned char* __restrict__ m, int* __restrict__ flag)
{
    __shared__ int sub4, oddw;
    if (threadIdx.x == 0) { sub4 = 0; oddw = 0; }
    __syncthreads();
    for (int j = threadIdx.x; j < BB*TT; j += blockDim.x) {
        unsigned char v = m[j];
        if (v) {
            if (j & 3) sub4 = 1;
            if ((j >> 2) & 1) oddw = 1;
        }
    }
    __syncthreads();
    if (threadIdx.x == 0) *flag = sub4 ? 1 : (oddw ? 0 : 2);
}

// ---------------------------------------------------------------------------
// fp32 -> bf16 conversion, 8 elems/thread. n8 = count/8.
// ---------------------------------------------------------------------------
__global__ __launch_bounds__(256) void cvt_kernel(
    const float* __restrict__ in, us16* __restrict__ out, int n8)
{
    int t = blockIdx.x*256 + threadIdx.x;
    if (t >= n8) return;
    const float4* s = (const float4*)(in + (long)t*8);
    float4 a = s[0], b = s[1];
    us16 tmp[8] = {f2b(a.x),f2b(a.y),f2b(a.z),f2b(a.w),f2b(b.x),f2b(b.y),f2b(b.z),f2b(b.w)};
    *(uint4*)(out + (long)t*8) = *(uint4*)tmp;
}

// Fused per-layer weight conversion.
__global__ __launch_bounds__(256) void cvt_layer_kernel(
    const float* __restrict__ qkv, const float* __restrict__ wo,
    const float* __restrict__ w1,  const float* __restrict__ w2,
    us16* __restrict__ dqkv, us16* __restrict__ dwo,
    us16* __restrict__ dw1,  us16* __restrict__ dw2)
{
    long t = (long)blockIdx.x*256 + threadIdx.x;
    const float* src; us16* dst; long off;
    if (t < 221184)      { src = qkv; dst = dqkv; off = t; }
    else if (t < 294912) { src = wo;  dst = dwo;  off = t - 221184; }
    else if (t < 589824) { src = w1;  dst = dw1;  off = t - 294912; }
    else                 { src = w2;  dst = dw2;  off = t - 589824; }
    const float4* s = (const float4*)(src + off*8);
    float4 a = s[0], b = s[1];
    us16 tmp[8] = {f2b(a.x),f2b(a.y),f2b(a.z),f2b(a.w),f2b(b.x),f2b(b.y),f2b(b.z),f2b(b.w)};
    *(uint4*)(dst + off*8) = *(uint4*)tmp;
}

// ---------------------------------------------------------------------------
// bf16 GEMM, m97-configuration: SINGLE 32KB LDS buffer, BK=64, 4 waves (2x2),
// __syncthreads drains, NATURAL register allocation (88 VGPR) -> ~5 blocks/CU
// via the LDS shrink alone; cross-block wave overlap hides the drain (m114).
// (Round-9 lesson: forcing occupancy via __launch_bounds__ min-waves capped
// VGPR at 48 and spilled the 64-VGPR accumulator to scratch -> 6x HBM traffic.)
//   out[m,n] = EPI( sum_k A[m,k]*W[n,k] + bias[n] )
// - global_load_lds dwordx4 staging (linear LDS dest).
// - Conflict-free XOR swizzle (round-5/6 proven, 0 conflicts): source col
//   block (lane&7)^(lane>>3) pre-swizzled on GLOBAL addr; read block
//   (kk*4+g)^(row&7).
// - Bijective XCD-aware grid remap (m204).
// EPI: 0 = store bf16, 1 = gelu->bf16, 2 = fp32 residual add (out += v)
// ---------------------------------------------------------------------------
template<int EPI>
__global__ __launch_bounds__(256) void gemm_bf(const us16* __restrict__ A,
    const us16* __restrict__ W, const float* __restrict__ bias,
    void* __restrict__ outv, int N, int K, int ntn)
{
    __shared__ us16 As[128*64];   // 16 KB
    __shared__ us16 Ws[128*64];   // 16 KB
    const int tid  = threadIdx.x;
    const int lane = tid & 63;
    const int wave = tid >> 6;
    const int wr = wave >> 1, wc = wave & 1;
    const int li = lane & 15, g = lane >> 4;

    // bijective XCD-aware remap (m204)
    const int nwg = gridDim.x;
    const int q8 = nwg >> 3, r8 = nwg & 7;
    const int xcd = blockIdx.x & 7, b8 = blockIdx.x >> 3;
    const int newlin = (xcd < r8 ? xcd*(q8+1) : r8*(q8+1) + (xcd - r8)*q8) + b8;
    const long tm = newlin / ntn, tn = newlin % ntn;

    // staging: chunk=wave*4+c covers rows chunk*8..+7; lane -> row chunk*8+(lane>>3),
    // source col block pre-swizzled: (lane&7)^(lane>>3)  [= (lane&7)^(row&7)]
    const int swzc = ((lane & 7) ^ (lane >> 3)) * 8;
    const us16* agp = A + (tm*128 + wave*32 + (lane>>3))*(long)K + swzc;
    const us16* wgp = W + (tn*128 + wave*32 + (lane>>3))*(long)K + swzc;

    // hoisted swizzled LDS read offsets (K-step-invariant)
    int aoff[2][4], woff[2][4];
    #pragma unroll
    for (int kk=0;kk<2;kk++) {
        #pragma unroll
        for (int mi=0;mi<4;mi++) {
            int r = wr*64 + mi*16 + li;
            aoff[kk][mi] = r*64 + ((kk*4 + g) ^ (r & 7))*8;
        }
        #pragma unroll
        for (int ni=0;ni<4;ni++) {
            int r = wc*64 + ni*16 + li;
            woff[kk][ni] = r*64 + ((kk*4 + g) ^ (r & 7))*8;
        }
    }

    f32x4 acc[4][4];
    #pragma unroll
    for (int i=0;i<4;i++)
        #pragma unroll
        for (int j=0;j<4;j++)
            #pragma unroll
            for (int r=0;r<4;r++) acc[i][j][r] = 0.f;

    for (int k0 = 0; k0 < K; k0 += 64) {
        #pragma unroll
        for (int c=0;c<4;c++) {
            gload16(agp + k0 + (long)c*8*K, &As[(wave*4+c)*512]);
            gload16(wgp + k0 + (long)c*8*K, &Ws[(wave*4+c)*512]);
        }
        __syncthreads();   // drains vmcnt(0): staged tile visible
        #pragma unroll
        for (int kk=0; kk<2; kk++) {
            bf16x8 afr[4], bfr[4];
            #pragma unroll
            for (int mi=0;mi<4;mi++) afr[mi] = *(const bf16x8*)(As + aoff[kk][mi]);
            #pragma unroll
            for (int ni=0;ni<4;ni++) bfr[ni] = *(const bf16x8*)(Ws + woff[kk][ni]);
            if (kk == 0) __builtin_amdgcn_s_setprio(1);
            #pragma unroll
            for (int mi=0;mi<4;mi++)
                #pragma unroll
                for (int ni=0;ni<4;ni++)
                    acc[mi][ni] = mfma16(afr[mi], bfr[ni], acc[mi][ni]);
        }
        __builtin_amdgcn_s_setprio(0);
        __syncthreads();   // reads retired before next stage overwrites
    }

    // epilogue: C layout col=lane&15, row=(lane>>4)*4+r
    const long rbase = tm*128 + wr*64 + (g*4);
    const long cbase = tn*128 + wc*64 + li;
    #pragma unroll
    for (int mi=0;mi<4;mi++) {
        #pragma unroll
        for (int ni=0;ni<4;ni++) {
            long col = cbase + ni*16;
            float bv = bias[col];
            #pragma unroll
            for (int r=0;r<4;r++) {
                long row = rbase + mi*16 + r;
                float v = acc[mi][ni][r] + bv;
                if constexpr (EPI == 0) {
                    ((us16*)outv)[row*(long)N + col] = f2b(v);
                } else if constexpr (EPI == 1) {
                    ((us16*)outv)[row*(long)N + col] = f2b(dgelu(v));
                } else {
                    float* o = (float*)outv;
                    o[row*(long)N + col] += v;
                }
            }
        }
    }
}

// ---------------------------------------------------------------------------
// Pack kernel: build fp32 residual stream h[b][62][768].
// ---------------------------------------------------------------------------
__global__ __launch_bounds__(256) void pack_kernel(
    const us16* __restrict__ e, const void* __restrict__ maskv,
    const int* __restrict__ flagp,
    const float* __restrict__ mod_emb, const float* __restrict__ day_emb,
    const float* __restrict__ readmit, const float* __restrict__ contrast,
    float* __restrict__ h, int* __restrict__ vlen_out)
{
    __shared__ int day_of[TT];
    __shared__ int nvalid;
    const int b = blockIdx.x, tid = threadIdx.x;
    if (tid == 0) {
        const int fl = *flagp;
        int c = 0;
        for (int t = 0; t < TT; t++) {
            int mv;
            if (fl == 1)      mv = ((const unsigned char*)maskv)[b*TT + t];
            else if (fl == 2) mv = ((const int*)maskv)[(b*TT + t)*2];
            else              mv = ((const int*)maskv)[b*TT + t];
            if (mv != 0) day_of[c++] = t;
        }
        nvalid = c;
        vlen_out[b] = 2*c;
    }
    __syncthreads();
    const int vl = 2*nvalid;
    for (int p = 0; p < SS; p++) {
        for (int d = tid; d < DM; d += 256) {
            float val;
            if (p < vl) {
                int day = day_of[p >> 1];
                int m = p & 1;
                int l = day*2 + m;
                val = b2f(e[((long)b*(TT*2) + l)*DM + d]) + mod_emb[m*DM + d] + day_emb[day*DM + d];
            } else if (p == vl || p == vl + 1) {
                float freq = expf(-(float)(d & ~1) * (9.2103403719761836f/768.f));
                float pe = (d & 1) ? cosf((float)p * freq) : sinf((float)p * freq);
                val = ((p == vl) ? readmit[d] : contrast[d]) + pe;
            } else {
                val = 0.f;
            }
            h[((long)b*SS + p)*DM + d] = val;
        }
    }
}

// ---------------------------------------------------------------------------
// LayerNorm: one wave per token row (768), fp32 in -> bf16 out (affine)
// ---------------------------------------------------------------------------
__global__ __launch_bounds__(256) void ln_kernel(
    const float* __restrict__ x, const float* __restrict__ w,
    const float* __restrict__ bprm, us16* __restrict__ z)
{
    const int row  = blockIdx.x*4 + (threadIdx.x >> 6);
    const int lane = threadIdx.x & 63;
    const float* xr = x + (long)row*DM;
    float4 v[3];
    float s = 0.f, s2 = 0.f;
    #pragma unroll
    for (int j=0;j<3;j++) {
        v[j] = *(const float4*)(xr + lane*4 + j*256);
        s  += v[j].x + v[j].y + v[j].z + v[j].w;
        s2 += v[j].x*v[j].x + v[j].y*v[j].y + v[j].z*v[j].z + v[j].w*v[j].w;
    }
    #pragma unroll
    for (int d=1; d<64; d<<=1) { s += __shfl_xor(s, d); s2 += __shfl_xor(s2, d); }
    const float m  = s * (1.f/768.f);
    const float var = s2 * (1.f/768.f) - m*m;
    const float rs = rsqrtf(var + 1e-5f);
    us16* zr = z + (long)row*DM;
    #pragma unroll
    for (int j=0;j<3;j++) {
        int c0 = lane*4 + j*256;
        float vv[4] = {v[j].x, v[j].y, v[j].z, v[j].w};
        ushort4 o;
        o.x = f2b((vv[0]-m)*rs*w[c0+0] + bprm[c0+0]);
        o.y = f2b((vv[1]-m)*rs*w[c0+1] + bprm[c0+1]);
        o.z = f2b((vv[2]-m)*rs*w[c0+2] + bprm[c0+2]);
        o.w = f2b((vv[3]-m)*rs*w[c0+3] + bprm[c0+3]);
        *(ushort4*)(zr + c0) = o;
    }
}

// ---------------------------------------------------------------------------
// Attention: one block (256 thr, 4 waves) per (batch, head). S=62 (pad 64).
// ---------------------------------------------------------------------------
__global__ __launch_bounds__(256) void attn_kernel(
    const us16* __restrict__ qkv, const int* __restrict__ vlenp,
    us16* __restrict__ ctx)
{
    __shared__ us16 Ql[64*64];
    __shared__ us16 Kl[64*64];
    __shared__ us16 Vt[64*64];
    __shared__ us16 Pl[4*16*64];
    const int b = blockIdx.x, hh = blockIdx.y;
    const int tid = threadIdx.x;
    const int vl = vlenp[b];

    {
        int s  = tid >> 2;
        int d0 = (tid & 3) * 16;
        if (s < SS) {
            long base = ((long)b*SS + s)*(3*DM) + hh*64 + d0;
            uint4 a0 = *(const uint4*)(qkv + base);
            uint4 a1 = *(const uint4*)(qkv + base + 8);
            *(uint4*)&Ql[s*64 + d0]     = a0;
            *(uint4*)&Ql[s*64 + d0 + 8] = a1;
            uint4 c0 = *(const uint4*)(qkv + base + DM);
            uint4 c1 = *(const uint4*)(qkv + base + DM + 8);
            *(uint4*)&Kl[s*64 + d0]     = c0;
            *(uint4*)&Kl[s*64 + d0 + 8] = c1;
            us16 vv[16];
            *(uint4*)&vv[0] = *(const uint4*)(qkv + base + 2*DM);
            *(uint4*)&vv[8] = *(const uint4*)(qkv + base + 2*DM + 8);
            #pragma unroll
            for (int j=0;j<16;j++) Vt[(d0+j)*64 + s] = vv[j];
        } else {
            uint4 zz = make_uint4(0,0,0,0);
            *(uint4*)&Ql[s*64 + d0] = zz; *(uint4*)&Ql[s*64 + d0 + 8] = zz;
            *(uint4*)&Kl[s*64 + d0] = zz; *(uint4*)&Kl[s*64 + d0 + 8] = zz;
            #pragma unroll
            for (int j=0;j<16;j++) Vt[(d0+j)*64 + s] = 0;
        }
    }
    __syncthreads();

    const int lane = tid & 63, wave = tid >> 6;
    const int li = lane & 15, g = lane >> 4;
    const int qbase = wave * 16;

    f32x4 sacc[4];
    #pragma unroll
    for (int kb=0; kb<4; kb++) {
        f32x4 a; a[0]=a[1]=a[2]=a[3]=0.f;
        #pragma unroll
        for (int dc=0; dc<2; dc++) {
            bf16x8 qa = *(const bf16x8*)&Ql[(qbase + li)*64 + dc*32 + g*8];
            bf16x8 ka = *(const bf16x8*)&Kl[(kb*16 + li)*64 + dc*32 + g*8];
            a = mfma16(qa, ka, a);
        }
        sacc[kb] = a;
    }

    float den[4];
    #pragma unroll
    for (int r=0;r<4;r++) {
        float sc[4]; float mx = -3e38f;
        #pragma unroll
        for (int kb=0;kb<4;kb++) {
            int key = kb*16 + li;
            float v = sacc[kb][r]*0.125f + ((key <= vl + 1) ? 0.f : -1e9f);
            sc[kb] = v; mx = fmaxf(mx, v);
        }
        #pragma unroll
        for (int d=1; d<16; d<<=1) mx = fmaxf(mx, __shfl_xor(mx, d));
        float sm = 0.f;
        #pragma unroll
        for (int kb=0;kb<4;kb++) {
            float e = expf(sc[kb] - mx);
            sm += e;
            Pl[wave*1024 + (g*4 + r)*64 + kb*16 + li] = f2b(e);
        }
        #pragma unroll
        for (int d=1; d<16; d<<=1) sm += __shfl_xor(sm, d);
        den[r] = sm;
    }
    __syncthreads();

    #pragma unroll
    for (int vb=0; vb<4; vb++) {
        f32x4 oa; oa[0]=oa[1]=oa[2]=oa[3]=0.f;
        #pragma unroll
        for (int kc=0; kc<2; kc++) {
            bf16x8 pa = *(const bf16x8*)&Pl[wave*1024 + li*64 + kc*32 + g*8];
            bf16x8 va = *(const bf16x8*)&Vt[(vb*16 + li)*64 + kc*32 + g*8];
            oa = mfma16(pa, va, oa);
        }
        #pragma unroll
        for (int r=0;r<4;r++) {
            int s = qbase + g*4 + r;
            if (s < SS)
                ctx[((long)b*SS + s)*DM + hh*64 + vb*16 + li] = f2b(oa[r] / den[r]);
        }
    }
}

// ---------------------------------------------------------------------------
// Head MLP
// ---------------------------------------------------------------------------
__global__ __launch_bounds__(384) void head_kernel(
    const float* __restrict__ h, const int* __restrict__ vlenp,
    const float* __restrict__ hW1, const float* __restrict__ hb1,
    const float* __restrict__ hlnw, const float* __restrict__ hlnb,
    const float* __restrict__ hW2, const float* __restrict__ hb2,
    float* __restrict__ out)
{
    __shared__ float tokS[DM];
    __shared__ float ps[6], ps2[6];
    const int b = blockIdx.x, tid = threadIdx.x;
    const float* tok = h + ((long)b*SS + vlenp[b])*DM;
    for (int i = tid; i < DM; i += 384) tokS[i] = tok[i];
    __syncthreads();

    const float* wrow = hW1 + (long)tid*DM;
    float acc = hb1[tid];
    for (int k = 0; k < DM; k += 4) {
        float4 wv = *(const float4*)(wrow + k);
        acc += tokS[k]*wv.x + tokS[k+1]*wv.y + tokS[k+2]*wv.z + tokS[k+3]*wv.w;
    }
    float s = acc, s2 = acc*acc;
    #pragma unroll
    for (int d=1; d<64; d<<=1) { s += __shfl_xor(s, d); s2 += __shfl_xor(s2, d); }
    const int wavei = tid >> 6, lane = tid & 63;
    if (lane == 0) { ps[wavei] = s; ps2[wavei] = s2; }
    __syncthreads();
    float S = 0.f, S2 = 0.f;
    for (int i=0;i<6;i++){ S += ps[i]; S2 += ps2[i]; }
    const float m = S * (1.f/384.f);
    const float var = S2 * (1.f/384.f) - m*m;
    const float rs = rsqrtf(var + 1e-5f);
    float z = (acc - m)*rs*hlnw[tid] + hlnb[tid];
    float part = dgelu(z) * hW2[tid];
    #pragma unroll
    for (int d=1; d<64; d<<=1) part += __shfl_xor(part, d);
    __syncthreads();
    if (lane == 0) ps[wavei] = part;
    __syncthreads();
    if (tid == 0) {
        float t = 0.f;
        for (int i=0;i<6;i++) t += ps[i];
        out[b] = t + hb2[0];
    }
}

// ---------------------------------------------------------------------------
extern "C" void kernel_launch(void* const* d_in, const int* in_sizes, int n_in,
                              void* d_out, int out_size, void* d_ws, size_t ws_size,
                              hipStream_t stream)
{
    (void)in_sizes; (void)n_in; (void)out_size; (void)ws_size;
    const float* x        = (const float*)d_in[0];
    const void*  mask     = d_in[1];
    const float* Wp       = (const float*)d_in[2];
    const float* bp       = (const float*)d_in[3];
    const float* mod_emb  = (const float*)d_in[4];
    const float* day_emb  = (const float*)d_in[5];
    const float* readmit  = (const float*)d_in[6];
    const float* contrast = (const float*)d_in[7];
    const float* WqkvS    = (const float*)d_in[8];
    const float* bqkvS    = (const float*)d_in[9];
    const float* WoS      = (const float*)d_in[10];
    const float* boS      = (const float*)d_in[11];
    const float* ln1w     = (const float*)d_in[12];
    const float* ln1b     = (const float*)d_in[13];
    const float* ln2w     = (const float*)d_in[14];
    const float* ln2b     = (const float*)d_in[15];
    const float* W1S      = (const float*)d_in[16];
    const float* b1S      = (const float*)d_in[17];
    const float* W2S      = (const float*)d_in[18];
    const float* b2S      = (const float*)d_in[19];
    const float* hW1      = (const float*)d_in[20];
    const float* hb1      = (const float*)d_in[21];
    const float* hlnw     = (const float*)d_in[22];
    const float* hlnb     = (const float*)d_in[23];
    const float* hW2      = (const float*)d_in[24];
    const float* hb2      = (const float*)d_in[25];
    float* out = (float*)d_out;

    // workspace layout (~193 MiB)
    char* ws = (char*)d_ws;
    float* h    = (float*)ws;                        // 48,758,784
    us16*  zb   = (us16*) (ws + 48758784);           // 24,379,392
    us16*  big  = (us16*) (ws + 73138176);           // 97,517,568 (qkv/ff/embed alias)
    us16*  wl   = (us16*) (ws + 170655744);          // 14,155,776 (per-layer bf16 weights)
    us16*  xb   = (us16*) (ws + 184811520);          // 7,864,320  (bf16 x)
    us16*  wpb  = (us16*) (ws + 192675840);          // 393,216    (bf16 Wp)
    int*   vlen = (int*)  (ws + 193069056);
    int*   mflag= (int*)  (ws + 193070080);
    us16*  qkvb = big;
    us16*  ffb  = big;
    us16*  eb   = big;
    us16* qkvw = wl;                         // 2304*768
    us16* wow  = wl + 1769472;               // 768*768
    us16* w1w  = wl + 2359296;               // 3072*768
    us16* w2w  = wl + 4718592;               // 768*3072

    detect_mask_kernel<<<1,256,0,stream>>>((const unsigned char*)mask, mflag);
    cvt_kernel<<<1920,256,0,stream>>>(x, xb, 491520);       // 15360*256/8
    cvt_kernel<<<96,256,0,stream>>>(Wp, wpb, 24576);        // 768*256/8
    // embed: e = gelu(x @ Wp^T + bp); grid 120*6=720
    gemm_bf<1><<<720,256,0,stream>>>(xb, wpb, bp, eb, DM, 256, 6);
    pack_kernel<<<256,256,0,stream>>>(eb, mask, mflag, mod_emb, day_emb, readmit, contrast, h, vlen);

    for (int l = 0; l < 12; l++) {
        cvt_layer_kernel<<<3456,256,0,stream>>>(
            WqkvS + (long)l*3*DM*DM, WoS + (long)l*DM*DM,
            W1S + (long)l*DFF*DM,    W2S + (long)l*DM*DFF,
            qkvw, wow, w1w, w2w);
        ln_kernel<<<NTOK/4,256,0,stream>>>(h, ln1w + l*DM, ln1b + l*DM, zb);
        gemm_bf<0><<<2232,256,0,stream>>>(zb, qkvw, bqkvS + l*3*DM, qkvb, 3*DM, DM, 18);   // 124*18
        attn_kernel<<<dim3(256,12),256,0,stream>>>(qkvb, vlen, zb);
        gemm_bf<2><<<744,256,0,stream>>>(zb, wow, boS + l*DM, h, DM, DM, 6);               // 124*6
        ln_kernel<<<NTOK/4,256,0,stream>>>(h, ln2w + l*DM, ln2b + l*DM, zb);
        gemm_bf<1><<<2976,256,0,stream>>>(zb, w1w, b1S + l*DFF, ffb, DFF, DM, 24);         // 124*24
        gemm_bf<2><<<744,256,0,stream>>>(ffb, w2w, b2S + l*DM, h, DM, DFF, 6);             // 124*6
    }

    head_kernel<<<256,384,0,stream>>>(h, vlen, hW1, hb1, hlnw, hlnb, hW2, hb2, out);
}